// Round 4
// baseline (14853.387 us; speedup 1.0000x reference)
//
#include <hip/hip_runtime.h>
#include <math.h>

#define BATCH 4
#define SEQ   2048
#define DIM   1024
#define NH    16
#define HD    64

// XOR-swizzled float index into row-major fp32 LDS tiles, addressed by
// 4-float chunk. XOR key = row >> log2(micro_rows): lanes that walk rows at
// stride micro_rows then land in distinct bank-sets (>=2-way max, free).
__device__ __forceinline__ int swz32_m8(int row, int chunk) {   // [R][32], 8-row micro
    return row * 32 + ((chunk ^ ((row >> 3) & 7)) << 2);
}
__device__ __forceinline__ int swz64(int row, int chunk) {      // [R][64], 4-row micro (attn)
    return row * 64 + ((chunk ^ ((row >> 2) & 7)) << 2);
}

// ---------------------------------------------------------------------------
// Kernel 1: fused Q/K/V projection (y = x @ W^T) + RoPE epilogue on q,k.
// Tile 128x64 (64 cols == one head), BK=32, 256 threads, 8x4 micro-tile,
// 3 accumulators (q,k,v) share the A-operand -> 384 FMA / ~340 LDS bytes.
// Output layout (B, H, S, HD).
// ---------------------------------------------------------------------------
__global__ __launch_bounds__(256) void qkv_rope_kernel(
    const float* __restrict__ x, const int* __restrict__ pos,
    const float* __restrict__ wq, const float* __restrict__ wk,
    const float* __restrict__ wv,
    float* __restrict__ qb, float* __restrict__ kb, float* __restrict__ vb)
{
    __shared__ __align__(16) float As [128 * 32];
    __shared__ __align__(16) float Bqs[64 * 32];
    __shared__ __align__(16) float Bks[64 * 32];
    __shared__ __align__(16) float Bvs[64 * 32];

    const int tid  = threadIdx.x;
    const int head = blockIdx.x;
    const int m0   = blockIdx.y * 128;
    const int n0   = head * 64;
    const int tx   = tid & 15, ty = tid >> 4;   // micro-tile: rows ty*8.., cols tx*4..
    const int r0   = tid >> 3;                  // staging row 0..31 (+32t)
    const int c0   = tid & 7;                   // staging chunk 0..7

    float accq[8][4] = {{0.f}}, acck[8][4] = {{0.f}}, accv[8][4] = {{0.f}};

    const float* xg = x  + (size_t)(m0 + r0) * DIM + c0 * 4;
    const float* qg = wq + (size_t)(n0 + r0) * DIM + c0 * 4;
    const float* kg = wk + (size_t)(n0 + r0) * DIM + c0 * 4;
    const float* vg = wv + (size_t)(n0 + r0) * DIM + c0 * 4;

    for (int k0 = 0; k0 < DIM; k0 += 32) {
        float4 a[4], bq[2], bk[2], bv[2];
        #pragma unroll
        for (int t = 0; t < 4; t++)
            a[t] = *(const float4*)(xg + (size_t)(32 * t) * DIM + k0);
        #pragma unroll
        for (int t = 0; t < 2; t++) {
            bq[t] = *(const float4*)(qg + (size_t)(32 * t) * DIM + k0);
            bk[t] = *(const float4*)(kg + (size_t)(32 * t) * DIM + k0);
            bv[t] = *(const float4*)(vg + (size_t)(32 * t) * DIM + k0);
        }
        __syncthreads();
        #pragma unroll
        for (int t = 0; t < 4; t++)
            *(float4*)&As[swz32_m8(r0 + 32 * t, c0)] = a[t];
        #pragma unroll
        for (int t = 0; t < 2; t++) {
            *(float4*)&Bqs[swz32_m8(r0 + 32 * t, c0)] = bq[t];
            *(float4*)&Bks[swz32_m8(r0 + 32 * t, c0)] = bk[t];
            *(float4*)&Bvs[swz32_m8(r0 + 32 * t, c0)] = bv[t];
        }
        __syncthreads();

        #pragma unroll
        for (int k4 = 0; k4 < 8; k4++) {
            float4 bqr[4], bkr[4], bvr[4];
            #pragma unroll
            for (int j = 0; j < 4; j++) {
                bqr[j] = *(const float4*)&Bqs[swz32_m8(tx * 4 + j, k4)];
                bkr[j] = *(const float4*)&Bks[swz32_m8(tx * 4 + j, k4)];
                bvr[j] = *(const float4*)&Bvs[swz32_m8(tx * 4 + j, k4)];
            }
            #pragma unroll
            for (int i = 0; i < 8; i++) {
                const float4 a4 = *(const float4*)&As[swz32_m8(ty * 8 + i, k4)];
                #pragma unroll
                for (int j = 0; j < 4; j++) {
                    accq[i][j] += a4.x*bqr[j].x + a4.y*bqr[j].y + a4.z*bqr[j].z + a4.w*bqr[j].w;
                    acck[i][j] += a4.x*bkr[j].x + a4.y*bkr[j].y + a4.z*bkr[j].z + a4.w*bkr[j].w;
                    accv[i][j] += a4.x*bvr[j].x + a4.y*bvr[j].y + a4.z*bvr[j].z + a4.w*bvr[j].w;
                }
            }
        }
    }

    // Epilogue: RoPE on q,k (pairs (d0,d0+1),(d0+2,d0+3)); v passthrough.
    const int d0 = tx * 4;                 // col within head
    const int p0 = d0 >> 1;                // pair indices p0, p0+1
    const float inv0 = powf(10000.0f, -(float)p0 / 32.0f);
    const float inv1 = powf(10000.0f, -(float)(p0 + 1) / 32.0f);
    #pragma unroll
    for (int i = 0; i < 8; i++) {
        const int m = m0 + ty * 8 + i;
        const int b = m >> 11;             // m / SEQ
        const int s = m & (SEQ - 1);
        const float pf = (float)pos[s];
        float sn0, cs0, sn1, cs1;
        sincosf(pf * inv0, &sn0, &cs0);
        sincosf(pf * inv1, &sn1, &cs1);
        const size_t base = (((size_t)b * NH + head) * SEQ + s) * HD + d0;
        float4 qo, ko;
        qo.x = accq[i][0] * cs0 - accq[i][1] * sn0;
        qo.y = accq[i][0] * sn0 + accq[i][1] * cs0;
        qo.z = accq[i][2] * cs1 - accq[i][3] * sn1;
        qo.w = accq[i][2] * sn1 + accq[i][3] * cs1;
        ko.x = acck[i][0] * cs0 - acck[i][1] * sn0;
        ko.y = acck[i][0] * sn0 + acck[i][1] * cs0;
        ko.z = acck[i][2] * cs1 - acck[i][3] * sn1;
        ko.w = acck[i][2] * sn1 + acck[i][3] * cs1;
        *(float4*)(qb + base) = qo;
        *(float4*)(kb + base) = ko;
        *(float4*)(vb + base) = make_float4(accv[i][0], accv[i][1], accv[i][2], accv[i][3]);
    }
}

// ---------------------------------------------------------------------------
// Kernel 2: causal flash attention, fp32 (UNCHANGED from audited baseline).
// One block per (b,h, 64-row q tile). QK^T and PV are 64x64x64 LDS GEMMs
// (4x4 micro-tile). Online softmax with 16-lane shfl_xor row reductions.
// P is wave-local (rows 16w..16w+15 live in wave w) -> no barrier needed
// between P write and PV read.
// ---------------------------------------------------------------------------
__global__ __launch_bounds__(256) void attn_kernel(
    const float* __restrict__ qb, const float* __restrict__ kb,
    const float* __restrict__ vb, float* __restrict__ hb)
{
    __shared__ __align__(16) float Qs[64][68];
    __shared__ __align__(16) float Ps[64][68];
    __shared__ __align__(16) float Ks[64 * 64];
    __shared__ __align__(16) float Vs[64 * 64];

    const int tid = threadIdx.x;
    const int qt  = blockIdx.x;
    const int bh  = blockIdx.y;
    const int q0  = qt * 64;
    const int tx  = tid & 15, ty = tid >> 4;

    const float* Qg = qb + ((size_t)bh * SEQ + q0) * HD;
    const float* Kg = kb + (size_t)bh * SEQ * HD;
    const float* Vg = vb + (size_t)bh * SEQ * HD;

    #pragma unroll
    for (int it = 0; it < 4; it++) {
        const int lin = tid + it * 256;          // 1024 float4s
        const int row = lin >> 4, ch = lin & 15;
        *(float4*)&Qs[row][ch * 4] = *(const float4*)(Qg + row * HD + ch * 4);
    }

    float m[4], l[4], o[4][4];
    #pragma unroll
    for (int i = 0; i < 4; i++) {
        m[i] = -INFINITY; l[i] = 0.f;
        #pragma unroll
        for (int j = 0; j < 4; j++) o[i][j] = 0.f;
    }

    for (int kt = 0; kt <= qt; kt++) {
        const int k0 = kt * 64;
        __syncthreads();
        #pragma unroll
        for (int it = 0; it < 4; it++) {
            const int lin = tid + it * 256;
            const int row = lin >> 4, ch = lin & 15;
            *(float4*)&Ks[swz64(row, ch)] = *(const float4*)(Kg + (size_t)(k0 + row) * HD + ch * 4);
            *(float4*)&Vs[swz64(row, ch)] = *(const float4*)(Vg + (size_t)(k0 + row) * HD + ch * 4);
        }
        __syncthreads();

        // S = Q K^T
        float sc[4][4] = {{0.f}};
        #pragma unroll
        for (int k4 = 0; k4 < 16; k4++) {
            float4 a4[4];
            #pragma unroll
            for (int i = 0; i < 4; i++)
                a4[i] = *(const float4*)&Qs[ty * 4 + i][k4 * 4];
            #pragma unroll
            for (int j = 0; j < 4; j++) {
                float4 b4 = *(const float4*)&Ks[swz64(tx * 4 + j, k4)];
                #pragma unroll
                for (int i = 0; i < 4; i++)
                    sc[i][j] += a4[i].x*b4.x + a4[i].y*b4.y + a4[i].z*b4.z + a4[i].w*b4.w;
            }
        }

        // scale + causal mask + online softmax
        #pragma unroll
        for (int i = 0; i < 4; i++) {
            const int qg = q0 + ty * 4 + i;
            #pragma unroll
            for (int j = 0; j < 4; j++) {
                const int kg = k0 + tx * 4 + j;
                sc[i][j] = (kg <= qg) ? sc[i][j] * 0.125f : -INFINITY;
            }
            float mt = fmaxf(fmaxf(sc[i][0], sc[i][1]), fmaxf(sc[i][2], sc[i][3]));
            mt = fmaxf(mt, __shfl_xor(mt, 1));
            mt = fmaxf(mt, __shfl_xor(mt, 2));
            mt = fmaxf(mt, __shfl_xor(mt, 4));
            mt = fmaxf(mt, __shfl_xor(mt, 8));
            const float mn = fmaxf(m[i], mt);        // finite: col k0 <= qg always valid
            const float alpha = __expf(m[i] - mn);   // first tile: exp(-inf)=0
            float p[4]; float ls = 0.f;
            #pragma unroll
            for (int j = 0; j < 4; j++) { p[j] = __expf(sc[i][j] - mn); ls += p[j]; }
            ls += __shfl_xor(ls, 1);
            ls += __shfl_xor(ls, 2);
            ls += __shfl_xor(ls, 4);
            ls += __shfl_xor(ls, 8);
            l[i] = l[i] * alpha + ls;
            m[i] = mn;
            #pragma unroll
            for (int j = 0; j < 4; j++) o[i][j] *= alpha;
            *(float4*)&Ps[ty * 4 + i][tx * 4] = make_float4(p[0], p[1], p[2], p[3]);
        }

        // O += P V  (P rows are same-wave, DS ops in-order per wave -> no barrier)
        #pragma unroll
        for (int k4 = 0; k4 < 16; k4++) {
            float4 a4[4];
            #pragma unroll
            for (int i = 0; i < 4; i++)
                a4[i] = *(const float4*)&Ps[ty * 4 + i][k4 * 4];
            float bv[4][4];
            #pragma unroll
            for (int u = 0; u < 4; u++) {
                float4 t = *(const float4*)&Vs[swz64(k4 * 4 + u, tx)];
                bv[u][0] = t.x; bv[u][1] = t.y; bv[u][2] = t.z; bv[u][3] = t.w;
            }
            #pragma unroll
            for (int i = 0; i < 4; i++)
                #pragma unroll
                for (int j = 0; j < 4; j++)
                    o[i][j] += a4[i].x*bv[0][j] + a4[i].y*bv[1][j] + a4[i].z*bv[2][j] + a4[i].w*bv[3][j];
        }
    }

    // epilogue: normalize, write h in (B, S, H, HD) == (B, S, D) layout
    const int b = bh >> 4, h = bh & 15;
    #pragma unroll
    for (int i = 0; i < 4; i++) {
        const float inv = 1.0f / l[i];
        const size_t base = (((size_t)b * SEQ + q0 + ty * 4 + i) * NH + h) * HD + tx * 4;
        *(float4*)(hb + base) = make_float4(o[i][0]*inv, o[i][1]*inv, o[i][2]*inv, o[i][3]*inv);
    }
}

// ---------------------------------------------------------------------------
// Kernel 3: out = h @ wo^T. Tile 128x128, BK=32, 256 threads, 8x8 micro-tile.
// 256 FMA / 256 LDS bytes per k4-step -> VALU-balanced.
// ---------------------------------------------------------------------------
__global__ __launch_bounds__(256) void out_gemm_kernel(
    const float* __restrict__ A, const float* __restrict__ W, float* __restrict__ C)
{
    __shared__ __align__(16) float As[128 * 32];
    __shared__ __align__(16) float Bs[128 * 32];

    const int tid = threadIdx.x;
    const int n0  = blockIdx.x * 128;
    const int m0  = blockIdx.y * 128;
    const int tx  = tid & 15, ty = tid >> 4;   // rows ty*8.., cols tx*8..
    const int r0  = tid >> 3, c0 = tid & 7;

    float acc[8][8] = {{0.f}};

    const float* ag = A + (size_t)(m0 + r0) * DIM + c0 * 4;
    const float* bg = W + (size_t)(n0 + r0) * DIM + c0 * 4;

    for (int k0 = 0; k0 < DIM; k0 += 32) {
        float4 a[4], b[4];
        #pragma unroll
        for (int t = 0; t < 4; t++) {
            a[t] = *(const float4*)(ag + (size_t)(32 * t) * DIM + k0);
            b[t] = *(const float4*)(bg + (size_t)(32 * t) * DIM + k0);
        }
        __syncthreads();
        #pragma unroll
        for (int t = 0; t < 4; t++) {
            *(float4*)&As[swz32_m8(r0 + 32 * t, c0)] = a[t];
            *(float4*)&Bs[swz32_m8(r0 + 32 * t, c0)] = b[t];
        }
        __syncthreads();

        #pragma unroll
        for (int k4 = 0; k4 < 8; k4++) {
            float4 br[8];
            #pragma unroll
            for (int j = 0; j < 8; j++)
                br[j] = *(const float4*)&Bs[swz32_m8(tx * 8 + j, k4)];
            #pragma unroll
            for (int i = 0; i < 8; i++) {
                const float4 a4 = *(const float4*)&As[swz32_m8(ty * 8 + i, k4)];
                #pragma unroll
                for (int j = 0; j < 8; j++)
                    acc[i][j] += a4.x*br[j].x + a4.y*br[j].y + a4.z*br[j].z + a4.w*br[j].w;
            }
        }
    }

    #pragma unroll
    for (int i = 0; i < 8; i++) {
        float* crow = C + (size_t)(m0 + ty * 8 + i) * DIM + n0 + tx * 8;
        *(float4*)(crow)     = make_float4(acc[i][0], acc[i][1], acc[i][2], acc[i][3]);
        *(float4*)(crow + 4) = make_float4(acc[i][4], acc[i][5], acc[i][6], acc[i][7]);
    }
}

// ---------------------------------------------------------------------------
extern "C" void kernel_launch(void* const* d_in, const int* in_sizes, int n_in,
                              void* d_out, int out_size, void* d_ws, size_t ws_size,
                              hipStream_t stream) {
    const float* x  = (const float*)d_in[0];
    const int*   pos = (const int*)d_in[1];
    const float* wq = (const float*)d_in[2];
    const float* wk = (const float*)d_in[3];
    const float* wv = (const float*)d_in[4];
    const float* wo = (const float*)d_in[5];
    float* out = (float*)d_out;

    // workspace: q, k, v in (B,H,S,HD) + h in (B,S,D); 4 x 32 MB = 128 MB
    const size_t n = (size_t)BATCH * SEQ * DIM;
    float* qb = (float*)d_ws;
    float* kb = qb + n;
    float* vb = kb + n;
    float* hb = vb + n;

    dim3 blk(256);
    qkv_rope_kernel<<<dim3(16, 64), blk, 0, stream>>>(x, pos, wq, wk, wv, qb, kb, vb);
    attn_kernel<<<dim3(32, 64), blk, 0, stream>>>(qb, kb, vb, hb);
    out_gemm_kernel<<<dim3(8, 64), blk, 0, stream>>>(hb, wo, out);
}

// Round 6
// 8873.748 us; speedup vs baseline: 1.6739x; 1.6739x over previous
//
#include <hip/hip_runtime.h>
#include <math.h>

#define BATCH 4
#define SEQ   2048
#define DIM   1024
#define NH    16
#define HD    64

// XOR-swizzled float index into row-major fp32 LDS tiles, addressed by
// 4-float chunk. XOR key = row >> log2(micro_rows): lanes that walk rows at
// stride micro_rows then land in distinct bank-sets (>=2-way max, free).
__device__ __forceinline__ int swz32_m8(int row, int chunk) {   // [R][32], 8-row micro
    return row * 32 + ((chunk ^ ((row >> 3) & 7)) << 2);
}
__device__ __forceinline__ int swz64(int row, int chunk) {      // [R][64], 4-row micro (attn)
    return row * 64 + ((chunk ^ ((row >> 2) & 7)) << 2);
}

// ---------------------------------------------------------------------------
// Kernel 1: projection y = x @ W^T for W in {wq,wk,wv} selected by blockIdx.z,
// 128x128 tile, BK=32, 256 threads, 8x8 micro-tile (proven no-spill structure
// from out_gemm: acc 64 + br 32 + staging 32 regs ~ 160 VGPR).
// RoPE fused into epilogue for z<2. Output layout (B, H, S, HD).
// Un-fused from the R3 version: the 3-accumulator fusion spilled (VGPR=256,
// 22 GB scratch writes, 10.4 ms). x re-read 3x from HBM costs only +64 MB.
// ---------------------------------------------------------------------------
__global__ __launch_bounds__(256) void proj_rope_kernel(
    const float* __restrict__ x, const int* __restrict__ pos,
    const float* __restrict__ wq, const float* __restrict__ wk,
    const float* __restrict__ wv,
    float* __restrict__ qb, float* __restrict__ kb, float* __restrict__ vb)
{
    __shared__ __align__(16) float As[128 * 32];
    __shared__ __align__(16) float Bs[128 * 32];

    const int z = blockIdx.z;
    const float* __restrict__ W = (z == 0) ? wq : (z == 1) ? wk : wv;
    float* __restrict__ outp    = (z == 0) ? qb : (z == 1) ? kb : vb;

    const int tid = threadIdx.x;
    const int n0  = blockIdx.x * 128;
    const int m0  = blockIdx.y * 128;
    const int tx  = tid & 15, ty = tid >> 4;   // rows ty*8.., cols tx*8..
    const int r0  = tid >> 3, c0 = tid & 7;

    float acc[8][8] = {{0.f}};

    const float* ag = x + (size_t)(m0 + r0) * DIM + c0 * 4;
    const float* bg = W + (size_t)(n0 + r0) * DIM + c0 * 4;

    for (int k0 = 0; k0 < DIM; k0 += 32) {
        float4 a[4], b[4];
        #pragma unroll
        for (int t = 0; t < 4; t++) {
            a[t] = *(const float4*)(ag + (size_t)(32 * t) * DIM + k0);
            b[t] = *(const float4*)(bg + (size_t)(32 * t) * DIM + k0);
        }
        __syncthreads();
        #pragma unroll
        for (int t = 0; t < 4; t++) {
            *(float4*)&As[swz32_m8(r0 + 32 * t, c0)] = a[t];
            *(float4*)&Bs[swz32_m8(r0 + 32 * t, c0)] = b[t];
        }
        __syncthreads();

        #pragma unroll
        for (int k4 = 0; k4 < 8; k4++) {
            float4 br[8];
            #pragma unroll
            for (int j = 0; j < 8; j++)
                br[j] = *(const float4*)&Bs[swz32_m8(tx * 8 + j, k4)];
            #pragma unroll
            for (int i = 0; i < 8; i++) {
                const float4 a4 = *(const float4*)&As[swz32_m8(ty * 8 + i, k4)];
                #pragma unroll
                for (int j = 0; j < 8; j++)
                    acc[i][j] += a4.x*br[j].x + a4.y*br[j].y + a4.z*br[j].z + a4.w*br[j].w;
            }
        }
    }

    // Epilogue: write to (B,H,S,HD); RoPE for q,k (z<2).
    // 8 consecutive cols tx*8..+7 stay within one 64-col head (8 | 64).
    const int head = (n0 + tx * 8) >> 6;
    const int d0   = (n0 + tx * 8) & 63;       // col-in-head, multiple of 8
    const int p0   = d0 >> 1;                  // first of 4 pair indices
    float invf[4];
    #pragma unroll
    for (int jj = 0; jj < 4; jj++)
        invf[jj] = powf(10000.0f, -(float)(p0 + jj) / 32.0f);

    #pragma unroll
    for (int i = 0; i < 8; i++) {
        const int m = m0 + ty * 8 + i;
        const int b = m >> 11;                 // m / SEQ
        const int s = m & (SEQ - 1);
        const size_t base = (((size_t)b * NH + head) * SEQ + s) * HD + d0;
        float v[8];
        #pragma unroll
        for (int j = 0; j < 8; j++) v[j] = acc[i][j];
        if (z < 2) {
            const float pf = (float)pos[s];
            #pragma unroll
            for (int jj = 0; jj < 4; jj++) {
                float sn, cs;
                sincosf(pf * invf[jj], &sn, &cs);
                const float x0 = acc[i][2 * jj], x1 = acc[i][2 * jj + 1];
                v[2 * jj]     = x0 * cs - x1 * sn;
                v[2 * jj + 1] = x0 * sn + x1 * cs;
            }
        }
        *(float4*)(outp + base)     = make_float4(v[0], v[1], v[2], v[3]);
        *(float4*)(outp + base + 4) = make_float4(v[4], v[5], v[6], v[7]);
    }
}

// ---------------------------------------------------------------------------
// Kernel 2: causal flash attention, fp32 (UNCHANGED, validated in R4 bench).
// One block per (b,h, 64-row q tile). QK^T and PV are 64x64x64 LDS GEMMs
// (4x4 micro-tile). Online softmax with 16-lane shfl_xor row reductions.
// P is wave-local (rows 16w..16w+15 live in wave w) -> no barrier needed
// between P write and PV read.
// ---------------------------------------------------------------------------
__global__ __launch_bounds__(256) void attn_kernel(
    const float* __restrict__ qb, const float* __restrict__ kb,
    const float* __restrict__ vb, float* __restrict__ hb)
{
    __shared__ __align__(16) float Qs[64][68];
    __shared__ __align__(16) float Ps[64][68];
    __shared__ __align__(16) float Ks[64 * 64];
    __shared__ __align__(16) float Vs[64 * 64];

    const int tid = threadIdx.x;
    const int qt  = blockIdx.x;
    const int bh  = blockIdx.y;
    const int q0  = qt * 64;
    const int tx  = tid & 15, ty = tid >> 4;

    const float* Qg = qb + ((size_t)bh * SEQ + q0) * HD;
    const float* Kg = kb + (size_t)bh * SEQ * HD;
    const float* Vg = vb + (size_t)bh * SEQ * HD;

    #pragma unroll
    for (int it = 0; it < 4; it++) {
        const int lin = tid + it * 256;          // 1024 float4s
        const int row = lin >> 4, ch = lin & 15;
        *(float4*)&Qs[row][ch * 4] = *(const float4*)(Qg + row * HD + ch * 4);
    }

    float m[4], l[4], o[4][4];
    #pragma unroll
    for (int i = 0; i < 4; i++) {
        m[i] = -INFINITY; l[i] = 0.f;
        #pragma unroll
        for (int j = 0; j < 4; j++) o[i][j] = 0.f;
    }

    for (int kt = 0; kt <= qt; kt++) {
        const int k0 = kt * 64;
        __syncthreads();
        #pragma unroll
        for (int it = 0; it < 4; it++) {
            const int lin = tid + it * 256;
            const int row = lin >> 4, ch = lin & 15;
            *(float4*)&Ks[swz64(row, ch)] = *(const float4*)(Kg + (size_t)(k0 + row) * HD + ch * 4);
            *(float4*)&Vs[swz64(row, ch)] = *(const float4*)(Vg + (size_t)(k0 + row) * HD + ch * 4);
        }
        __syncthreads();

        // S = Q K^T
        float sc[4][4] = {{0.f}};
        #pragma unroll
        for (int k4 = 0; k4 < 16; k4++) {
            float4 a4[4];
            #pragma unroll
            for (int i = 0; i < 4; i++)
                a4[i] = *(const float4*)&Qs[ty * 4 + i][k4 * 4];
            #pragma unroll
            for (int j = 0; j < 4; j++) {
                float4 b4 = *(const float4*)&Ks[swz64(tx * 4 + j, k4)];
                #pragma unroll
                for (int i = 0; i < 4; i++)
                    sc[i][j] += a4[i].x*b4.x + a4[i].y*b4.y + a4[i].z*b4.z + a4[i].w*b4.w;
            }
        }

        // scale + causal mask + online softmax
        #pragma unroll
        for (int i = 0; i < 4; i++) {
            const int qg = q0 + ty * 4 + i;
            #pragma unroll
            for (int j = 0; j < 4; j++) {
                const int kg = k0 + tx * 4 + j;
                sc[i][j] = (kg <= qg) ? sc[i][j] * 0.125f : -INFINITY;
            }
            float mt = fmaxf(fmaxf(sc[i][0], sc[i][1]), fmaxf(sc[i][2], sc[i][3]));
            mt = fmaxf(mt, __shfl_xor(mt, 1));
            mt = fmaxf(mt, __shfl_xor(mt, 2));
            mt = fmaxf(mt, __shfl_xor(mt, 4));
            mt = fmaxf(mt, __shfl_xor(mt, 8));
            const float mn = fmaxf(m[i], mt);        // finite: col k0 <= qg always valid
            const float alpha = __expf(m[i] - mn);   // first tile: exp(-inf)=0
            float p[4]; float ls = 0.f;
            #pragma unroll
            for (int j = 0; j < 4; j++) { p[j] = __expf(sc[i][j] - mn); ls += p[j]; }
            ls += __shfl_xor(ls, 1);
            ls += __shfl_xor(ls, 2);
            ls += __shfl_xor(ls, 4);
            ls += __shfl_xor(ls, 8);
            l[i] = l[i] * alpha + ls;
            m[i] = mn;
            #pragma unroll
            for (int j = 0; j < 4; j++) o[i][j] *= alpha;
            *(float4*)&Ps[ty * 4 + i][tx * 4] = make_float4(p[0], p[1], p[2], p[3]);
        }

        // O += P V  (P rows are same-wave, DS ops in-order per wave -> no barrier)
        #pragma unroll
        for (int k4 = 0; k4 < 16; k4++) {
            float4 a4[4];
            #pragma unroll
            for (int i = 0; i < 4; i++)
                a4[i] = *(const float4*)&Ps[ty * 4 + i][k4 * 4];
            float bv[4][4];
            #pragma unroll
            for (int u = 0; u < 4; u++) {
                float4 t = *(const float4*)&Vs[swz64(k4 * 4 + u, tx)];
                bv[u][0] = t.x; bv[u][1] = t.y; bv[u][2] = t.z; bv[u][3] = t.w;
            }
            #pragma unroll
            for (int i = 0; i < 4; i++)
                #pragma unroll
                for (int j = 0; j < 4; j++)
                    o[i][j] += a4[i].x*bv[0][j] + a4[i].y*bv[1][j] + a4[i].z*bv[2][j] + a4[i].w*bv[3][j];
        }
    }

    // epilogue: normalize, write h in (B, S, H, HD) == (B, S, D) layout
    const int b = bh >> 4, h = bh & 15;
    #pragma unroll
    for (int i = 0; i < 4; i++) {
        const float inv = 1.0f / l[i];
        const size_t base = (((size_t)b * SEQ + q0 + ty * 4 + i) * NH + h) * HD + tx * 4;
        *(float4*)(hb + base) = make_float4(o[i][0]*inv, o[i][1]*inv, o[i][2]*inv, o[i][3]*inv);
    }
}

// ---------------------------------------------------------------------------
// Kernel 3: out = h @ wo^T. Tile 128x128, BK=32, 256 threads, 8x8 micro-tile.
// (UNCHANGED, validated in R4 bench.)
// ---------------------------------------------------------------------------
__global__ __launch_bounds__(256) void out_gemm_kernel(
    const float* __restrict__ A, const float* __restrict__ W, float* __restrict__ C)
{
    __shared__ __align__(16) float As[128 * 32];
    __shared__ __align__(16) float Bs[128 * 32];

    const int tid = threadIdx.x;
    const int n0  = blockIdx.x * 128;
    const int m0  = blockIdx.y * 128;
    const int tx  = tid & 15, ty = tid >> 4;   // rows ty*8.., cols tx*8..
    const int r0  = tid >> 3, c0 = tid & 7;

    float acc[8][8] = {{0.f}};

    const float* ag = A + (size_t)(m0 + r0) * DIM + c0 * 4;
    const float* bg = W + (size_t)(n0 + r0) * DIM + c0 * 4;

    for (int k0 = 0; k0 < DIM; k0 += 32) {
        float4 a[4], b[4];
        #pragma unroll
        for (int t = 0; t < 4; t++) {
            a[t] = *(const float4*)(ag + (size_t)(32 * t) * DIM + k0);
            b[t] = *(const float4*)(bg + (size_t)(32 * t) * DIM + k0);
        }
        __syncthreads();
        #pragma unroll
        for (int t = 0; t < 4; t++) {
            *(float4*)&As[swz32_m8(r0 + 32 * t, c0)] = a[t];
            *(float4*)&Bs[swz32_m8(r0 + 32 * t, c0)] = b[t];
        }
        __syncthreads();

        #pragma unroll
        for (int k4 = 0; k4 < 8; k4++) {
            float4 br[8];
            #pragma unroll
            for (int j = 0; j < 8; j++)
                br[j] = *(const float4*)&Bs[swz32_m8(tx * 8 + j, k4)];
            #pragma unroll
            for (int i = 0; i < 8; i++) {
                const float4 a4 = *(const float4*)&As[swz32_m8(ty * 8 + i, k4)];
                #pragma unroll
                for (int j = 0; j < 8; j++)
                    acc[i][j] += a4.x*br[j].x + a4.y*br[j].y + a4.z*br[j].z + a4.w*br[j].w;
            }
        }
    }

    #pragma unroll
    for (int i = 0; i < 8; i++) {
        float* crow = C + (size_t)(m0 + ty * 8 + i) * DIM + n0 + tx * 8;
        *(float4*)(crow)     = make_float4(acc[i][0], acc[i][1], acc[i][2], acc[i][3]);
        *(float4*)(crow + 4) = make_float4(acc[i][4], acc[i][5], acc[i][6], acc[i][7]);
    }
}

// ---------------------------------------------------------------------------
extern "C" void kernel_launch(void* const* d_in, const int* in_sizes, int n_in,
                              void* d_out, int out_size, void* d_ws, size_t ws_size,
                              hipStream_t stream) {
    const float* x  = (const float*)d_in[0];
    const int*   pos = (const int*)d_in[1];
    const float* wq = (const float*)d_in[2];
    const float* wk = (const float*)d_in[3];
    const float* wv = (const float*)d_in[4];
    const float* wo = (const float*)d_in[5];
    float* out = (float*)d_out;

    // workspace: q, k, v in (B,H,S,HD) + h in (B,S,D); 4 x 32 MB = 128 MB
    const size_t n = (size_t)BATCH * SEQ * DIM;
    float* qb = (float*)d_ws;
    float* kb = qb + n;
    float* vb = kb + n;
    float* hb = vb + n;

    dim3 blk(256);
    proj_rope_kernel<<<dim3(8, 64, 3), blk, 0, stream>>>(x, pos, wq, wk, wv, qb, kb, vb);
    attn_kernel<<<dim3(32, 64), blk, 0, stream>>>(qb, kb, vb, hb);
    out_gemm_kernel<<<dim3(8, 64), blk, 0, stream>>>(hb, wo, out);
}

// Round 8
// 4364.934 us; speedup vs baseline: 3.4029x; 2.0330x over previous
//
#include <hip/hip_runtime.h>
#include <math.h>

#define BATCH 4
#define SEQ   2048
#define DIM   1024
#define NH    16
#define HD    64

// XOR-swizzled float index into row-major fp32 LDS tiles, addressed by
// 4-float chunk (read side). LDS position p within a row holds global chunk
// p ^ key(row); the XOR is an involution, so reads use the same mapping.
__device__ __forceinline__ int swz32_m8(int row, int chunk) {   // [R][32] floats
    return row * 32 + ((chunk ^ ((row >> 3) & 7)) << 2);
}
__device__ __forceinline__ int swz64(int row, int chunk) {      // [R][64] floats
    return row * 64 + ((chunk ^ ((row >> 2) & 7)) << 2);
}

// Direct global->LDS 16B DMA: linear LDS dest (wave-uniform base + lane*16B),
// per-lane global source. Source chunk is pre-XOR'd so swizzled content lands
// at linear positions (rule: linear dest + inverse-swz source + swz on read).
__device__ __forceinline__ void gload_lds16(const float* g, float* l) {
    __builtin_amdgcn_global_load_lds(
        (const __attribute__((address_space(1))) void*)g,
        (__attribute__((address_space(3))) void*)l, 16, 0, 0);
}

// ---------------------------------------------------------------------------
// Kernel 1: projection y = x @ W^T for W in {wq,wk,wv} selected by blockIdx.z,
// 128x128 tile, BK=32, 256 threads, 8x8 micro-tile. Staging via
// global_load_lds (no staging VGPRs, no ds_write bank conflicts); #pragma
// unroll 2 on k4 bounds the ds_read hoist window (R6: full unroll + staging
// regs spilled at VGPR=256 with 15.5 GB scratch traffic).
// RoPE fused into epilogue for z<2. Output layout (B, H, S, HD).
// ---------------------------------------------------------------------------
__global__ __launch_bounds__(256) void proj_rope_kernel(
    const float* __restrict__ x, const int* __restrict__ pos,
    const float* __restrict__ wq, const float* __restrict__ wk,
    const float* __restrict__ wv,
    float* __restrict__ qb, float* __restrict__ kb, float* __restrict__ vb)
{
    __shared__ __align__(16) float As[128 * 32];
    __shared__ __align__(16) float Bs[128 * 32];

    const int z = blockIdx.z;
    const float* __restrict__ W = (z == 0) ? wq : (z == 1) ? wk : wv;
    float* __restrict__ outp    = (z == 0) ? qb : (z == 1) ? kb : vb;

    const int tid  = threadIdx.x;
    const int n0   = blockIdx.x * 128;
    const int m0   = blockIdx.y * 128;
    const int tx   = tid & 15, ty = tid >> 4;   // micro-tile rows ty*8.., cols tx*8..
    const int wv_  = tid >> 6;                  // wave id 0..3
    const int lane = tid & 63;
    const int rr   = lane >> 3;                 // 0..7 (row within wave's 8-row slab)
    const int cc   = lane & 7;                  // 0..7 (16B chunk)

    float acc[8][8] = {{0.f}};

    // Staging plan, t=0..3: wave wv_ covers rows [t*32 + wv_*8, +8).
    // key(t) = ((t*32+wv_*8+rr)>>3)&7 = (t*4+wv_)&7 (wave-uniform).
    const float* ax[4]; const float* bx[4]; float* al[4]; float* bl[4];
    #pragma unroll
    for (int t = 0; t < 4; t++) {
        const int row = t * 32 + wv_ * 8 + rr;
        const int key = (t * 4 + wv_) & 7;
        ax[t] = x + (size_t)(m0 + row) * DIM + ((cc ^ key) << 2);
        bx[t] = W + (size_t)(n0 + row) * DIM + ((cc ^ key) << 2);
        al[t] = &As[(t * 32 + wv_ * 8) * 32];
        bl[t] = &Bs[(t * 32 + wv_ * 8) * 32];
    }

    for (int k0 = 0; k0 < DIM; k0 += 32) {
        #pragma unroll
        for (int t = 0; t < 4; t++) {
            gload_lds16(ax[t] + k0, al[t]);
            gload_lds16(bx[t] + k0, bl[t]);
        }
        __syncthreads();   // drains vmcnt -> LDS tiles complete

        #pragma unroll 2
        for (int k4 = 0; k4 < 8; k4++) {
            float4 br[8];
            #pragma unroll
            for (int j = 0; j < 8; j++)
                br[j] = *(const float4*)&Bs[swz32_m8(tx * 8 + j, k4)];
            #pragma unroll
            for (int i = 0; i < 8; i++) {
                const float4 a4 = *(const float4*)&As[swz32_m8(ty * 8 + i, k4)];
                #pragma unroll
                for (int j = 0; j < 8; j++)
                    acc[i][j] += a4.x*br[j].x + a4.y*br[j].y + a4.z*br[j].z + a4.w*br[j].w;
            }
        }
        __syncthreads();   // protect LDS before next stage
    }

    // Epilogue: write to (B,H,S,HD); RoPE for q,k (z<2).
    const int head = (n0 + tx * 8) >> 6;
    const int d0   = (n0 + tx * 8) & 63;       // col-in-head, multiple of 8
    const int p0   = d0 >> 1;                  // first of 4 pair indices
    float invf[4];
    #pragma unroll
    for (int jj = 0; jj < 4; jj++)
        invf[jj] = powf(10000.0f, -(float)(p0 + jj) / 32.0f);

    #pragma unroll
    for (int i = 0; i < 8; i++) {
        const int m = m0 + ty * 8 + i;
        const int b = m >> 11;                 // m / SEQ
        const int s = m & (SEQ - 1);
        const size_t base = (((size_t)b * NH + head) * SEQ + s) * HD + d0;
        float v[8];
        #pragma unroll
        for (int j = 0; j < 8; j++) v[j] = acc[i][j];
        if (z < 2) {
            const float pf = (float)pos[s];
            #pragma unroll
            for (int jj = 0; jj < 4; jj++) {
                float sn, cs;
                sincosf(pf * invf[jj], &sn, &cs);
                const float x0 = acc[i][2 * jj], x1 = acc[i][2 * jj + 1];
                v[2 * jj]     = x0 * cs - x1 * sn;
                v[2 * jj + 1] = x0 * sn + x1 * cs;
            }
        }
        *(float4*)(outp + base)     = make_float4(v[0], v[1], v[2], v[3]);
        *(float4*)(outp + base + 4) = make_float4(v[4], v[5], v[6], v[7]);
    }
}

// ---------------------------------------------------------------------------
// Kernel 2: causal flash attention, fp32. Compute/softmax structure UNCHANGED
// (validated R4/R6); K/V staging switched to global_load_lds with pre-swizzled
// source (identical LDS content/layout as before; removes the 8-way
// ds_write_b128 bank conflict and staging registers).
// ---------------------------------------------------------------------------
__global__ __launch_bounds__(256) void attn_kernel(
    const float* __restrict__ qb, const float* __restrict__ kb,
    const float* __restrict__ vb, float* __restrict__ hb)
{
    __shared__ __align__(16) float Qs[64][68];
    __shared__ __align__(16) float Ps[64][68];
    __shared__ __align__(16) float Ks[64 * 64];
    __shared__ __align__(16) float Vs[64 * 64];

    const int tid = threadIdx.x;
    const int qt  = blockIdx.x;
    const int bh  = blockIdx.y;
    const int q0  = qt * 64;
    const int tx  = tid & 15, ty = tid >> 4;

    const float* Qg = qb + ((size_t)bh * SEQ + q0) * HD;
    const float* Kg = kb + (size_t)bh * SEQ * HD;
    const float* Vg = vb + (size_t)bh * SEQ * HD;

    #pragma unroll
    for (int it = 0; it < 4; it++) {
        const int lin = tid + it * 256;          // 1024 float4s
        const int row = lin >> 4, ch = lin & 15;
        *(float4*)&Qs[row][ch * 4] = *(const float4*)(Qg + row * HD + ch * 4);
    }

    // K/V staging plan, t=0..3: wave wv_ covers rows [t*16 + wv_*4, +4).
    // key = ((t*16+wv_*4+krr)>>2)&7 = (t*4+wv_)&7 (wave-uniform).
    const int wv_  = tid >> 6;
    const int lane = tid & 63;
    const int krr  = lane >> 4;                 // 0..3
    const int kcc  = lane & 15;                 // 0..15
    const float* kx[4]; const float* vx[4]; float* kl[4]; float* vl[4];
    #pragma unroll
    for (int t = 0; t < 4; t++) {
        const int row = t * 16 + wv_ * 4 + krr;
        const int key = (t * 4 + wv_) & 7;
        kx[t] = Kg + (size_t)row * HD + ((kcc ^ key) << 2);
        vx[t] = Vg + (size_t)row * HD + ((kcc ^ key) << 2);
        kl[t] = &Ks[(t * 16 + wv_ * 4) * 64];
        vl[t] = &Vs[(t * 16 + wv_ * 4) * 64];
    }

    float m[4], l[4], o[4][4];
    #pragma unroll
    for (int i = 0; i < 4; i++) {
        m[i] = -INFINITY; l[i] = 0.f;
        #pragma unroll
        for (int j = 0; j < 4; j++) o[i][j] = 0.f;
    }

    for (int kt = 0; kt <= qt; kt++) {
        const size_t koff = (size_t)(kt * 64) * HD;
        __syncthreads();
        #pragma unroll
        for (int t = 0; t < 4; t++) {
            gload_lds16(kx[t] + koff, kl[t]);
            gload_lds16(vx[t] + koff, vl[t]);
        }
        __syncthreads();

        // S = Q K^T
        float sc[4][4] = {{0.f}};
        #pragma unroll
        for (int k4 = 0; k4 < 16; k4++) {
            float4 a4[4];
            #pragma unroll
            for (int i = 0; i < 4; i++)
                a4[i] = *(const float4*)&Qs[ty * 4 + i][k4 * 4];
            #pragma unroll
            for (int j = 0; j < 4; j++) {
                float4 b4 = *(const float4*)&Ks[swz64(tx * 4 + j, k4)];
                #pragma unroll
                for (int i = 0; i < 4; i++)
                    sc[i][j] += a4[i].x*b4.x + a4[i].y*b4.y + a4[i].z*b4.z + a4[i].w*b4.w;
            }
        }

        // scale + causal mask + online softmax
        const int k0 = kt * 64;
        #pragma unroll
        for (int i = 0; i < 4; i++) {
            const int qg = q0 + ty * 4 + i;
            #pragma unroll
            for (int j = 0; j < 4; j++) {
                const int kg = k0 + tx * 4 + j;
                sc[i][j] = (kg <= qg) ? sc[i][j] * 0.125f : -INFINITY;
            }
            float mt = fmaxf(fmaxf(sc[i][0], sc[i][1]), fmaxf(sc[i][2], sc[i][3]));
            mt = fmaxf(mt, __shfl_xor(mt, 1));
            mt = fmaxf(mt, __shfl_xor(mt, 2));
            mt = fmaxf(mt, __shfl_xor(mt, 4));
            mt = fmaxf(mt, __shfl_xor(mt, 8));
            const float mn = fmaxf(m[i], mt);        // finite: col k0 <= qg always valid
            const float alpha = __expf(m[i] - mn);   // first tile: exp(-inf)=0
            float p[4]; float ls = 0.f;
            #pragma unroll
            for (int j = 0; j < 4; j++) { p[j] = __expf(sc[i][j] - mn); ls += p[j]; }
            ls += __shfl_xor(ls, 1);
            ls += __shfl_xor(ls, 2);
            ls += __shfl_xor(ls, 4);
            ls += __shfl_xor(ls, 8);
            l[i] = l[i] * alpha + ls;
            m[i] = mn;
            #pragma unroll
            for (int j = 0; j < 4; j++) o[i][j] *= alpha;
            *(float4*)&Ps[ty * 4 + i][tx * 4] = make_float4(p[0], p[1], p[2], p[3]);
        }

        // O += P V  (P rows are same-wave, DS ops in-order per wave -> no barrier)
        #pragma unroll
        for (int k4 = 0; k4 < 16; k4++) {
            float4 a4[4];
            #pragma unroll
            for (int i = 0; i < 4; i++)
                a4[i] = *(const float4*)&Ps[ty * 4 + i][k4 * 4];
            float bv[4][4];
            #pragma unroll
            for (int u = 0; u < 4; u++) {
                float4 t = *(const float4*)&Vs[swz64(k4 * 4 + u, tx)];
                bv[u][0] = t.x; bv[u][1] = t.y; bv[u][2] = t.z; bv[u][3] = t.w;
            }
            #pragma unroll
            for (int i = 0; i < 4; i++)
                #pragma unroll
                for (int j = 0; j < 4; j++)
                    o[i][j] += a4[i].x*bv[0][j] + a4[i].y*bv[1][j] + a4[i].z*bv[2][j] + a4[i].w*bv[3][j];
        }
    }

    // epilogue: normalize, write h in (B, S, H, HD) == (B, S, D) layout
    const int b = bh >> 4, h = bh & 15;
    #pragma unroll
    for (int i = 0; i < 4; i++) {
        const float inv = 1.0f / l[i];
        const size_t base = (((size_t)b * SEQ + q0 + ty * 4 + i) * NH + h) * HD + tx * 4;
        *(float4*)(hb + base) = make_float4(o[i][0]*inv, o[i][1]*inv, o[i][2]*inv, o[i][3]*inv);
    }
}

// ---------------------------------------------------------------------------
// Kernel 3: out = h @ wo^T. Same restructure as proj (global_load_lds staging,
// unroll-2 inner loop), no RoPE, row-major output.
// ---------------------------------------------------------------------------
__global__ __launch_bounds__(256) void out_gemm_kernel(
    const float* __restrict__ A, const float* __restrict__ W, float* __restrict__ C)
{
    __shared__ __align__(16) float As[128 * 32];
    __shared__ __align__(16) float Bs[128 * 32];

    const int tid  = threadIdx.x;
    const int n0   = blockIdx.x * 128;
    const int m0   = blockIdx.y * 128;
    const int tx   = tid & 15, ty = tid >> 4;
    const int wv_  = tid >> 6;
    const int lane = tid & 63;
    const int rr   = lane >> 3;
    const int cc   = lane & 7;

    float acc[8][8] = {{0.f}};

    const float* ax[4]; const float* bx[4]; float* al[4]; float* bl[4];
    #pragma unroll
    for (int t = 0; t < 4; t++) {
        const int row = t * 32 + wv_ * 8 + rr;
        const int key = (t * 4 + wv_) & 7;
        ax[t] = A + (size_t)(m0 + row) * DIM + ((cc ^ key) << 2);
        bx[t] = W + (size_t)(n0 + row) * DIM + ((cc ^ key) << 2);
        al[t] = &As[(t * 32 + wv_ * 8) * 32];
        bl[t] = &Bs[(t * 32 + wv_ * 8) * 32];
    }

    for (int k0 = 0; k0 < DIM; k0 += 32) {
        #pragma unroll
        for (int t = 0; t < 4; t++) {
            gload_lds16(ax[t] + k0, al[t]);
            gload_lds16(bx[t] + k0, bl[t]);
        }
        __syncthreads();

        #pragma unroll 2
        for (int k4 = 0; k4 < 8; k4++) {
            float4 br[8];
            #pragma unroll
            for (int j = 0; j < 8; j++)
                br[j] = *(const float4*)&Bs[swz32_m8(tx * 8 + j, k4)];
            #pragma unroll
            for (int i = 0; i < 8; i++) {
                const float4 a4 = *(const float4*)&As[swz32_m8(ty * 8 + i, k4)];
                #pragma unroll
                for (int j = 0; j < 8; j++)
                    acc[i][j] += a4.x*br[j].x + a4.y*br[j].y + a4.z*br[j].z + a4.w*br[j].w;
            }
        }
        __syncthreads();
    }

    #pragma unroll
    for (int i = 0; i < 8; i++) {
        float* crow = C + (size_t)(m0 + ty * 8 + i) * DIM + n0 + tx * 8;
        *(float4*)(crow)     = make_float4(acc[i][0], acc[i][1], acc[i][2], acc[i][3]);
        *(float4*)(crow + 4) = make_float4(acc[i][4], acc[i][5], acc[i][6], acc[i][7]);
    }
}

// ---------------------------------------------------------------------------
extern "C" void kernel_launch(void* const* d_in, const int* in_sizes, int n_in,
                              void* d_out, int out_size, void* d_ws, size_t ws_size,
                              hipStream_t stream) {
    const float* x  = (const float*)d_in[0];
    const int*   pos = (const int*)d_in[1];
    const float* wq = (const float*)d_in[2];
    const float* wk = (const float*)d_in[3];
    const float* wv = (const float*)d_in[4];
    const float* wo = (const float*)d_in[5];
    float* out = (float*)d_out;

    // workspace: q, k, v in (B,H,S,HD) + h in (B,S,D); 4 x 32 MB = 128 MB
    const size_t n = (size_t)BATCH * SEQ * DIM;
    float* qb = (float*)d_ws;
    float* kb = qb + n;
    float* vb = kb + n;
    float* hb = vb + n;

    dim3 blk(256);
    proj_rope_kernel<<<dim3(8, 64, 3), blk, 0, stream>>>(x, pos, wq, wk, wv, qb, kb, vb);
    attn_kernel<<<dim3(32, 64), blk, 0, stream>>>(qb, kb, vb, hb);
    out_gemm_kernel<<<dim3(8, 64), blk, 0, stream>>>(hb, wo, out);
}

// Round 11
// 2282.452 us; speedup vs baseline: 6.5076x; 1.9124x over previous
//
#include <hip/hip_runtime.h>
#include <math.h>

#define BATCH 4
#define SEQ   2048
#define DIM   1024
#define NH    16
#define HD    64

// XOR-swizzled float index into row-major fp32 LDS tiles, addressed by
// 4-float chunk (read side). LDS position p within a row holds global chunk
// p ^ key(row); the XOR is an involution, so reads use the same mapping.
__device__ __forceinline__ int swz32_m8(int row, int chunk) {   // [R][32] floats
    return row * 32 + ((chunk ^ ((row >> 3) & 7)) << 2);
}
__device__ __forceinline__ int swz64(int row, int chunk) {      // [R][64] floats
    return row * 64 + ((chunk ^ ((row >> 2) & 7)) << 2);
}

// Direct global->LDS 16B DMA: linear LDS dest (wave-uniform base + lane*16B),
// per-lane global source. Source chunk is pre-XOR'd so swizzled content lands
// at linear positions (rule: linear dest + inverse-swz source + swz on read).
__device__ __forceinline__ void gload_lds16(const float* g, float* l) {
    __builtin_amdgcn_global_load_lds(
        (const __attribute__((address_space(1))) void*)g,
        (__attribute__((address_space(3))) void*)l, 16, 0, 0);
}

// ---------------------------------------------------------------------------
// Kernel 1: projection y = x @ W^T for W in {wq,wk,wv} selected by blockIdx.z,
// 128x128 tile, BK=32, 256 threads, 8x8 micro-tile. Staging via
// global_load_lds; unroll-2 inner loop bounds the ds_read hoist window.
// (Validated R8: proj no longer in top-5.)
// ---------------------------------------------------------------------------
__global__ __launch_bounds__(256) void proj_rope_kernel(
    const float* __restrict__ x, const int* __restrict__ pos,
    const float* __restrict__ wq, const float* __restrict__ wk,
    const float* __restrict__ wv,
    float* __restrict__ qb, float* __restrict__ kb, float* __restrict__ vb)
{
    __shared__ __align__(16) float As[128 * 32];
    __shared__ __align__(16) float Bs[128 * 32];

    const int z = blockIdx.z;
    const float* __restrict__ W = (z == 0) ? wq : (z == 1) ? wk : wv;
    float* __restrict__ outp    = (z == 0) ? qb : (z == 1) ? kb : vb;

    const int tid  = threadIdx.x;
    const int n0   = blockIdx.x * 128;
    const int m0   = blockIdx.y * 128;
    const int tx   = tid & 15, ty = tid >> 4;
    const int wv_  = tid >> 6;
    const int lane = tid & 63;
    const int rr   = lane >> 3;
    const int cc   = lane & 7;

    float acc[8][8] = {{0.f}};

    const float* ax[4]; const float* bx[4]; float* al[4]; float* bl[4];
    #pragma unroll
    for (int t = 0; t < 4; t++) {
        const int row = t * 32 + wv_ * 8 + rr;
        const int key = (t * 4 + wv_) & 7;
        ax[t] = x + (size_t)(m0 + row) * DIM + ((cc ^ key) << 2);
        bx[t] = W + (size_t)(n0 + row) * DIM + ((cc ^ key) << 2);
        al[t] = &As[(t * 32 + wv_ * 8) * 32];
        bl[t] = &Bs[(t * 32 + wv_ * 8) * 32];
    }

    for (int k0 = 0; k0 < DIM; k0 += 32) {
        #pragma unroll
        for (int t = 0; t < 4; t++) {
            gload_lds16(ax[t] + k0, al[t]);
            gload_lds16(bx[t] + k0, bl[t]);
        }
        __syncthreads();

        #pragma unroll 2
        for (int k4 = 0; k4 < 8; k4++) {
            float4 br[8];
            #pragma unroll
            for (int j = 0; j < 8; j++)
                br[j] = *(const float4*)&Bs[swz32_m8(tx * 8 + j, k4)];
            #pragma unroll
            for (int i = 0; i < 8; i++) {
                const float4 a4 = *(const float4*)&As[swz32_m8(ty * 8 + i, k4)];
                #pragma unroll
                for (int j = 0; j < 8; j++)
                    acc[i][j] += a4.x*br[j].x + a4.y*br[j].y + a4.z*br[j].z + a4.w*br[j].w;
            }
        }
        __syncthreads();
    }

    const int head = (n0 + tx * 8) >> 6;
    const int d0   = (n0 + tx * 8) & 63;
    const int p0   = d0 >> 1;
    float invf[4];
    #pragma unroll
    for (int jj = 0; jj < 4; jj++)
        invf[jj] = powf(10000.0f, -(float)(p0 + jj) / 32.0f);

    #pragma unroll
    for (int i = 0; i < 8; i++) {
        const int m = m0 + ty * 8 + i;
        const int b = m >> 11;
        const int s = m & (SEQ - 1);
        const size_t base = (((size_t)b * NH + head) * SEQ + s) * HD + d0;
        float v[8];
        #pragma unroll
        for (int j = 0; j < 8; j++) v[j] = acc[i][j];
        if (z < 2) {
            const float pf = (float)pos[s];
            #pragma unroll
            for (int jj = 0; jj < 4; jj++) {
                float sn, cs;
                sincosf(pf * invf[jj], &sn, &cs);
                const float x0 = acc[i][2 * jj], x1 = acc[i][2 * jj + 1];
                v[2 * jj]     = x0 * cs - x1 * sn;
                v[2 * jj + 1] = x0 * sn + x1 * cs;
            }
        }
        *(float4*)(outp + base)     = make_float4(v[0], v[1], v[2], v[3]);
        *(float4*)(outp + base + 4) = make_float4(v[4], v[5], v[6], v[7]);
    }
}

// ---------------------------------------------------------------------------
// Kernel 2: causal flash attention, fp32. R8 showed VGPR=256 + 1.35 GB
// scratch writes: the fully-unrolled k4 loops let the scheduler hoist LDS
// reads across the whole body -> spill. Fix: #pragma unroll 4 bounds the
// in-flight ds_read window (same cure as proj R6->R8). Heavy blocks (large
// qt) dispatch first via reversed blockIdx.x to shrink the tail.
// ---------------------------------------------------------------------------
__global__ __launch_bounds__(256) void attn_kernel(
    const float* __restrict__ qb, const float* __restrict__ kb,
    const float* __restrict__ vb, float* __restrict__ hb)
{
    __shared__ __align__(16) float Qs[64][68];
    __shared__ __align__(16) float Ps[64][68];
    __shared__ __align__(16) float Ks[64 * 64];
    __shared__ __align__(16) float Vs[64 * 64];

    const int tid = threadIdx.x;
    const int qt  = (int)gridDim.x - 1 - (int)blockIdx.x;   // heavy first
    const int bh  = blockIdx.y;
    const int q0  = qt * 64;
    const int tx  = tid & 15, ty = tid >> 4;

    const float* Qg = qb + ((size_t)bh * SEQ + q0) * HD;
    const float* Kg = kb + (size_t)bh * SEQ * HD;
    const float* Vg = vb + (size_t)bh * SEQ * HD;

    #pragma unroll
    for (int it = 0; it < 4; it++) {
        const int lin = tid + it * 256;          // 1024 float4s
        const int row = lin >> 4, ch = lin & 15;
        *(float4*)&Qs[row][ch * 4] = *(const float4*)(Qg + row * HD + ch * 4);
    }

    // K/V staging plan, t=0..3: wave wv_ covers rows [t*16 + wv_*4, +4).
    const int wv_  = tid >> 6;
    const int lane = tid & 63;
    const int krr  = lane >> 4;
    const int kcc  = lane & 15;
    const float* kx[4]; const float* vx[4]; float* kl[4]; float* vl[4];
    #pragma unroll
    for (int t = 0; t < 4; t++) {
        const int row = t * 16 + wv_ * 4 + krr;
        const int key = (t * 4 + wv_) & 7;
        kx[t] = Kg + (size_t)row * HD + ((kcc ^ key) << 2);
        vx[t] = Vg + (size_t)row * HD + ((kcc ^ key) << 2);
        kl[t] = &Ks[(t * 16 + wv_ * 4) * 64];
        vl[t] = &Vs[(t * 16 + wv_ * 4) * 64];
    }

    float m[4], l[4], o[4][4];
    #pragma unroll
    for (int i = 0; i < 4; i++) {
        m[i] = -INFINITY; l[i] = 0.f;
        #pragma unroll
        for (int j = 0; j < 4; j++) o[i][j] = 0.f;
    }

    for (int kt = 0; kt <= qt; kt++) {
        const size_t koff = (size_t)(kt * 64) * HD;
        __syncthreads();
        #pragma unroll
        for (int t = 0; t < 4; t++) {
            gload_lds16(kx[t] + koff, kl[t]);
            gload_lds16(vx[t] + koff, vl[t]);
        }
        __syncthreads();

        // S = Q K^T  (unroll 4: bounds hoisted ds_read live range)
        float sc[4][4] = {{0.f}};
        #pragma unroll 4
        for (int k4 = 0; k4 < 16; k4++) {
            float4 a4[4];
            #pragma unroll
            for (int i = 0; i < 4; i++)
                a4[i] = *(const float4*)&Qs[ty * 4 + i][k4 * 4];
            #pragma unroll
            for (int j = 0; j < 4; j++) {
                float4 b4 = *(const float4*)&Ks[swz64(tx * 4 + j, k4)];
                #pragma unroll
                for (int i = 0; i < 4; i++)
                    sc[i][j] += a4[i].x*b4.x + a4[i].y*b4.y + a4[i].z*b4.z + a4[i].w*b4.w;
            }
        }

        // scale + causal mask + online softmax
        const int k0 = kt * 64;
        #pragma unroll
        for (int i = 0; i < 4; i++) {
            const int qg = q0 + ty * 4 + i;
            #pragma unroll
            for (int j = 0; j < 4; j++) {
                const int kg = k0 + tx * 4 + j;
                sc[i][j] = (kg <= qg) ? sc[i][j] * 0.125f : -INFINITY;
            }
            float mt = fmaxf(fmaxf(sc[i][0], sc[i][1]), fmaxf(sc[i][2], sc[i][3]));
            mt = fmaxf(mt, __shfl_xor(mt, 1));
            mt = fmaxf(mt, __shfl_xor(mt, 2));
            mt = fmaxf(mt, __shfl_xor(mt, 4));
            mt = fmaxf(mt, __shfl_xor(mt, 8));
            const float mn = fmaxf(m[i], mt);        // finite: col k0 <= qg always valid
            const float alpha = __expf(m[i] - mn);   // first tile: exp(-inf)=0
            float p[4]; float ls = 0.f;
            #pragma unroll
            for (int j = 0; j < 4; j++) { p[j] = __expf(sc[i][j] - mn); ls += p[j]; }
            ls += __shfl_xor(ls, 1);
            ls += __shfl_xor(ls, 2);
            ls += __shfl_xor(ls, 4);
            ls += __shfl_xor(ls, 8);
            l[i] = l[i] * alpha + ls;
            m[i] = mn;
            #pragma unroll
            for (int j = 0; j < 4; j++) o[i][j] *= alpha;
            *(float4*)&Ps[ty * 4 + i][tx * 4] = make_float4(p[0], p[1], p[2], p[3]);
        }

        // O += P V  (P rows are same-wave; unroll 4 bounds live range)
        #pragma unroll 4
        for (int k4 = 0; k4 < 16; k4++) {
            float4 a4[4];
            #pragma unroll
            for (int i = 0; i < 4; i++)
                a4[i] = *(const float4*)&Ps[ty * 4 + i][k4 * 4];
            float bv[4][4];
            #pragma unroll
            for (int u = 0; u < 4; u++) {
                float4 t = *(const float4*)&Vs[swz64(k4 * 4 + u, tx)];
                bv[u][0] = t.x; bv[u][1] = t.y; bv[u][2] = t.z; bv[u][3] = t.w;
            }
            #pragma unroll
            for (int i = 0; i < 4; i++)
                #pragma unroll
                for (int j = 0; j < 4; j++)
                    o[i][j] += a4[i].x*bv[0][j] + a4[i].y*bv[1][j] + a4[i].z*bv[2][j] + a4[i].w*bv[3][j];
        }
    }

    // epilogue: normalize, write h in (B, S, H, HD) == (B, S, D) layout
    const int b = bh >> 4, h = bh & 15;
    #pragma unroll
    for (int i = 0; i < 4; i++) {
        const float inv = 1.0f / l[i];
        const size_t base = (((size_t)b * SEQ + q0 + ty * 4 + i) * NH + h) * HD + tx * 4;
        *(float4*)(hb + base) = make_float4(o[i][0]*inv, o[i][1]*inv, o[i][2]*inv, o[i][3]*inv);
    }
}

// ---------------------------------------------------------------------------
// Kernel 3: out = h @ wo^T. Same structure as proj (validated R8).
// ---------------------------------------------------------------------------
__global__ __launch_bounds__(256) void out_gemm_kernel(
    const float* __restrict__ A, const float* __restrict__ W, float* __restrict__ C)
{
    __shared__ __align__(16) float As[128 * 32];
    __shared__ __align__(16) float Bs[128 * 32];

    const int tid  = threadIdx.x;
    const int n0   = blockIdx.x * 128;
    const int m0   = blockIdx.y * 128;
    const int tx   = tid & 15, ty = tid >> 4;
    const int wv_  = tid >> 6;
    const int lane = tid & 63;
    const int rr   = lane >> 3;
    const int cc   = lane & 7;

    float acc[8][8] = {{0.f}};

    const float* ax[4]; const float* bx[4]; float* al[4]; float* bl[4];
    #pragma unroll
    for (int t = 0; t < 4; t++) {
        const int row = t * 32 + wv_ * 8 + rr;
        const int key = (t * 4 + wv_) & 7;
        ax[t] = A + (size_t)(m0 + row) * DIM + ((cc ^ key) << 2);
        bx[t] = W + (size_t)(n0 + row) * DIM + ((cc ^ key) << 2);
        al[t] = &As[(t * 32 + wv_ * 8) * 32];
        bl[t] = &Bs[(t * 32 + wv_ * 8) * 32];
    }

    for (int k0 = 0; k0 < DIM; k0 += 32) {
        #pragma unroll
        for (int t = 0; t < 4; t++) {
            gload_lds16(ax[t] + k0, al[t]);
            gload_lds16(bx[t] + k0, bl[t]);
        }
        __syncthreads();

        #pragma unroll 2
        for (int k4 = 0; k4 < 8; k4++) {
            float4 br[8];
            #pragma unroll
            for (int j = 0; j < 8; j++)
                br[j] = *(const float4*)&Bs[swz32_m8(tx * 8 + j, k4)];
            #pragma unroll
            for (int i = 0; i < 8; i++) {
                const float4 a4 = *(const float4*)&As[swz32_m8(ty * 8 + i, k4)];
                #pragma unroll
                for (int j = 0; j < 8; j++)
                    acc[i][j] += a4.x*br[j].x + a4.y*br[j].y + a4.z*br[j].z + a4.w*br[j].w;
            }
        }
        __syncthreads();
    }

    #pragma unroll
    for (int i = 0; i < 8; i++) {
        float* crow = C + (size_t)(m0 + ty * 8 + i) * DIM + n0 + tx * 8;
        *(float4*)(crow)     = make_float4(acc[i][0], acc[i][1], acc[i][2], acc[i][3]);
        *(float4*)(crow + 4) = make_float4(acc[i][4], acc[i][5], acc[i][6], acc[i][7]);
    }
}

// ---------------------------------------------------------------------------
extern "C" void kernel_launch(void* const* d_in, const int* in_sizes, int n_in,
                              void* d_out, int out_size, void* d_ws, size_t ws_size,
                              hipStream_t stream) {
    const float* x  = (const float*)d_in[0];
    const int*   pos = (const int*)d_in[1];
    const float* wq = (const float*)d_in[2];
    const float* wk = (const float*)d_in[3];
    const float* wv = (const float*)d_in[4];
    const float* wo = (const float*)d_in[5];
    float* out = (float*)d_out;

    // workspace: q, k, v in (B,H,S,HD) + h in (B,S,D); 4 x 32 MB = 128 MB
    const size_t n = (size_t)BATCH * SEQ * DIM;
    float* qb = (float*)d_ws;
    float* kb = qb + n;
    float* vb = kb + n;
    float* hb = vb + n;

    dim3 blk(256);
    proj_rope_kernel<<<dim3(8, 64, 3), blk, 0, stream>>>(x, pos, wq, wk, wv, qb, kb, vb);
    attn_kernel<<<dim3(32, 64), blk, 0, stream>>>(qb, kb, vb, hb);
    out_gemm_kernel<<<dim3(8, 64), blk, 0, stream>>>(hb, wo, out);
}